// Round 5
// baseline (205.670 us; speedup 1.0000x reference)
//
#include <hip/hip_runtime.h>

// Y = (Bm@A) @ a_term + (Bm@C) @ c_term as one bf16 MFMA GEMM.
// R9 == R8 resubmitted (round 4 was an infra failure, no kernel verdict).
// R8: latency-structure fix. (1) acat is emitted by prep_kernel already in
// MFMA fragment order, so main_kernel stages it with a verbatim lane-linear
// 16 KB copy (conflict-free) and afrag ds_read_b128 are lane-linear (2-way =
// free, no swizzle). (2) Wave timeline reordered: acat loads issued first,
// J/X per-lane loads second, acat->LDS write (vmcnt: only oldest 4 must
// land), phase-1 geometry covers the J/X HBM latency, and the single
// __syncthreads() sits AFTER phase 1, right before the MFMA loop. (3) All
// manual lgkmcnt(0) drains removed - same-wave LDS is in-order, compiler
// inserts minimal waits. (4) launch_bounds(256,5): 29,440 B x 5 = 147 KB LDS,
// 20 waves/CU.
// Per-block LDS (dwords): [0..4095] acat (fragment order), then 4 x 816
// per-wave Z/epilogue slots (wave-private, no barriers needed).

typedef __bf16 bf16x8 __attribute__((ext_vector_type(8)));
typedef float floatx4 __attribute__((ext_vector_type(4)));

#define ZRS  68   // Z row stride in dwords
#define WLDS 816  // per-wave LDS dwords (12 Z rows x 68; epilogue aliases)

__global__ __launch_bounds__(64) void prep_kernel(const float* __restrict__ A,
                                                  const float* __restrict__ Bm,
                                                  const float* __restrict__ C,
                                                  __bf16* __restrict__ acat) {
    int tid = blockIdx.x * 64 + threadIdx.x;  // 0..4095, one wave per block
    int f = tid >> 6;
    int e = tid & 63;
    float m = 0.f, m2 = 0.f;
    #pragma unroll 8
    for (int k = 0; k < 64; ++k) {
        float b = Bm[f * 64 + k];
        m  = fmaf(b, A[k * 64 + e], m);
        m2 = fmaf(b, C[k * 64 + e], m2);
    }
    // logical row-major element (f, k): k=2e -> M[f,e], k=2e+1 -> M2[f,e].
    // stored in MFMA fragment order:
    //   p(f,k) = ((mt*4 + kc)*64 + quad*16 + l15)*8 + (k&7)
    //   mt=f>>4, l15=f&15, kc=k>>5, quad=(k>>3)&3
    int mt  = f >> 4, l15 = f & 15;
    int k1  = 2 * e;
    int kc  = k1 >> 5;
    int qd  = (k1 >> 3) & 3;
    int j   = k1 & 7;  // even, so j+1 stays in the same 8-elem group
    int p   = ((mt * 4 + kc) * 64 + qd * 16 + l15) * 8 + j;
    acat[p]     = (__bf16)m;
    acat[p + 1] = (__bf16)m2;
}

static __device__ __forceinline__ unsigned pk(float a, float c) {
    unsigned short ua = __builtin_bit_cast(unsigned short, (__bf16)a);
    unsigned short uc = __builtin_bit_cast(unsigned short, (__bf16)c);
    return ((unsigned)uc << 16) | ua;
}

__global__ __launch_bounds__(256, 5) void main_kernel(const float* __restrict__ X,
                                                      const float* __restrict__ J,
                                                      const __bf16* __restrict__ acat,
                                                      float* __restrict__ out) {
    __shared__ __align__(16) float lds[4096 + 4 * WLDS];  // 29,440 B

    const int tid  = threadIdx.x;
    const int wave = tid >> 6;
    const int lane = tid & 63;
    const int l15  = lane & 15;
    const int quad = lane >> 4;
    const int pbase = blockIdx.x * 16 + wave * 4;  // 4 points per wave

    // ---- acat loads FIRST (L2-hot; must be oldest in the vmcnt queue) ----
    const floatx4* ag = (const floatx4*)acat;  // 1024 float4, fragment order
    floatx4 t0 = ag[tid];
    floatx4 t1 = ag[256 + tid];
    floatx4 t2 = ag[512 + tid];
    floatx4 t3 = ag[768 + tid];

    // ---- per-lane direct J/X loads (HBM; latency hides under phase 1) ----
    float2 jreg[4][3];
    float  xreg[4][3];
    {
        const float* Jb = J + (size_t)pbase * 384 + lane * 6;   // lane = d
        const float* Xb = X + (size_t)pbase * 192 + lane * 3;
        #pragma unroll
        for (int pi = 0; pi < 4; ++pi) {
            jreg[pi][0] = *(const float2*)(Jb + pi * 384);
            jreg[pi][1] = *(const float2*)(Jb + pi * 384 + 2);
            jreg[pi][2] = *(const float2*)(Jb + pi * 384 + 4);
            xreg[pi][0] = Xb[pi * 192];
            xreg[pi][1] = Xb[pi * 192 + 1];
            xreg[pi][2] = Xb[pi * 192 + 2];
        }
    }

    // ---- acat -> LDS, verbatim linear copy (stride-1, conflict-free) ----
    {
        floatx4* al = (floatx4*)lds;
        al[tid]       = t0;
        al[256 + tid] = t1;
        al[512 + tid] = t2;
        al[768 + tid] = t3;
    }

    float* zbase = lds + 4096 + wave * WLDS;

    // ---- phase 1: pure-register geometry, lane = d ----
    #pragma unroll
    for (int pi = 0; pi < 4; ++pi) {
        float a0x = jreg[pi][0].x, a1x = jreg[pi][0].y;  // record [i][j] row-major
        float a0y = jreg[pi][1].x, a1y = jreg[pi][1].y;
        float a0z = jreg[pi][2].x, a1z = jreg[pi][2].y;
        float xx = xreg[pi][0], xy = xreg[pi][1], xz = xreg[pi][2];

        float n0 = sqrtf(a0x * a0x + a0y * a0y + a0z * a0z);
        float r0 = 1.0f / fmaxf(n0, 1e-12f);
        float b1x = a0x * r0, b1y = a0y * r0, b1z = a0z * r0;

        float d  = b1x * a1x + b1y * a1y + b1z * a1z;
        float ux = a1x - d * b1x, uy = a1y - d * b1y, uz = a1z - d * b1z;
        float n2 = sqrtf(ux * ux + uy * uy + uz * uz);
        float r2 = 1.0f / fmaxf(n2, 1e-12f);
        float b2x = ux * r2, b2y = uy * r2, b2z = uz * r2;

        float b3x = b1y * b2z - b1z * b2y;
        float b3y = b1z * b2x - b1x * b2z;
        float b3z = b1x * b2y - b1y * b2x;

        float rt0 = b1x * xx + b1y * xy + b1z * xz;
        float rt1 = b2x * xx + b2y * xy + b2z * xz;
        float rt2 = b3x * xx + b3y * xy + b3z * xz;

        float s = rt1 - rt2, tt = rt1 + rt2;

        unsigned* zr = (unsigned*)zbase + pi * (3 * ZRS);  // rows (pi, 0..2)
        zr[lane]           = pk(b2x * s + b3x * tt, b1x * rt0);
        zr[ZRS + lane]     = pk(b2y * s + b3y * tt, b1y * rt0);
        zr[2 * ZRS + lane] = pk(b2z * s + b3z * tt, b1z * rt0);
    }

    // acat visible block-wide; Z rows are wave-private (in-order DS).
    __syncthreads();

    // ---- phase 2: 16x mfma 16x16x32, K=128, rows 0..11 valid ----
    floatx4 acc[4];
    #pragma unroll
    for (int mt = 0; mt < 4; ++mt) acc[mt] = (floatx4){0.f, 0.f, 0.f, 0.f};

    int row = l15 > 11 ? 11 : l15;  // clamp: n>=12 columns are garbage, never stored
    int pz  = (row * 21846) >> 16;  // row / 3
    int iz  = row - pz * 3;
    const __bf16* zb   = (const __bf16*)zbase + pz * (3 * ZRS * 2) + iz * (ZRS * 2);
    const __bf16* albf = (const __bf16*)lds;
    #pragma unroll
    for (int kc = 0; kc < 4; ++kc) {
        bf16x8 b = *(const bf16x8*)(zb + kc * 32 + quad * 8);
        #pragma unroll
        for (int mt = 0; mt < 4; ++mt) {
            bf16x8 a = *(const bf16x8*)(albf + ((mt * 4 + kc) * 64 + lane) * 8);
            acc[mt] = __builtin_amdgcn_mfma_f32_16x16x32_bf16(a, b, acc[mt], 0, 0, 0);
        }
    }

    // ---- epilogue: D[f][n] -> LDS [p_local*196 + f*3 + i] (aliases Z region) ----
    float* dl = zbase;
    #pragma unroll
    for (int mt = 0; mt < 4; ++mt) {
        int n = l15;
        if (n < 12) {
            int pl = (n * 21846) >> 16;  // n / 3
            int i  = n - pl * 3;
            float* dst = dl + pl * 196 + i;
            #pragma unroll
            for (int r = 0; r < 4; ++r) {
                int f = mt * 16 + quad * 4 + r;
                dst[f * 3] = acc[mt][r];
            }
        }
    }

    // ---- coalesced store: 4 points x 48 float4 = 192 float4 ----
    // (same-wave LDS in-order: reads below see the scatter writes above)
    floatx4* og = (floatx4*)(out + (size_t)pbase * 192);
    #pragma unroll
    for (int t = 0; t < 3; ++t) {
        int g  = t * 64 + lane;
        int pg = (g * 1366) >> 16;  // g / 48
        int o  = g - pg * 48;
        og[g] = *(const floatx4*)(dl + pg * 196 + o * 4);
    }
}

extern "C" void kernel_launch(void* const* d_in, const int* in_sizes, int n_in,
                              void* d_out, int out_size, void* d_ws, size_t ws_size,
                              hipStream_t stream) {
    const float* X  = (const float*)d_in[0];
    const float* J  = (const float*)d_in[1];
    const float* A  = (const float*)d_in[2];
    const float* Bm = (const float*)d_in[3];
    const float* C  = (const float*)d_in[4];
    float* out = (float*)d_out;
    __bf16* acat = (__bf16*)d_ws;  // 64x128 bf16 = 16 KB, fragment order

    prep_kernel<<<64, 64, 0, stream>>>(A, Bm, C, acat);

    // 65536 points = 4096 blocks x 4 waves x 4 points
    main_kernel<<<4096, 256, 0, stream>>>(X, J, acat, out);
}